// Round 13
// baseline (162.528 us; speedup 1.0000x reference)
//
#include <hip/hip_runtime.h>
#include <hip/hip_bf16.h>

#define FIN 128
#define FOUT 64
#define TILE_ROWS 64       // rows per gemm block = 4 waves x 16

#define EPB 2048           // edges per sort chunk
#define NPB 16             // nodes per bucket (d >> 4)
#define NBUK_MAX 3200
#define CAP 448            // records cap per bucket (mean 256, +12 sigma)

// Workspace layout (bytes, 16B-aligned):
//   [0, 6,400,000)             support : N*64 bf16
//   [6,400,000, +16,384)       Wt      : 64x128 bf16 (W transposed)
//   [6,416,384, +4,900,000)    hist    : SBP*NBUK int, CHUNK-major [c][j]
//   [11,316,384, +12,500)      btot    : NBUK int (per-bucket totals)
//   [11,328,896, +12,504)      off     : (NBUK+1) int (bucket base offsets)
//   [11,341,408, +6,400,000)   tmp     : E int2 {src | dloc<<16, ev}
#define OFF_WT   6400000
#define OFF_HIST 6416384
#define OFF_BTOT 11316384
#define OFF_OFF  11328896
#define OFF_TMP  11341408

typedef short bf16x8 __attribute__((ext_vector_type(8)));
typedef float f32x4  __attribute__((ext_vector_type(4)));

__device__ inline ushort f32_to_bf16_rne(float f) {
    unsigned u = __float_as_uint(f);
    u += 0x7FFFu + ((u >> 16) & 1u);
    return (ushort)(u >> 16);
}
__device__ inline float bf16_to_f32(ushort h) {
    return __uint_as_float((unsigned)h << 16);
}

// ---------------------------------------------------------------------------
// prep: Wt[n][k] = bf16(W[k][n])  (16 KB, L1-resident for the gemm kernel)
// ---------------------------------------------------------------------------
__global__ __launch_bounds__(256) void prep_wt_kernel(
    const float* __restrict__ W, ushort* __restrict__ Wt)
{
    const int tid = threadIdx.x;
    for (int i = 0; i < 32; ++i) {
        int flat = i * 256 + tid;
        int k = flat >> 6;
        int n = flat & 63;
        Wt[n * FIN + k] = f32_to_bf16_rne(W[flat]);
    }
}

// ---------------------------------------------------------------------------
// Fused: blocks [0,GB) MFMA gemm; blocks [GB,..) coarse dst histogram with
// CONTIGUOUS row writes (hist[c][j], chunk-major).
// ---------------------------------------------------------------------------
__global__ __launch_bounds__(256) void gemm_hist_kernel(
    const float* __restrict__ x, const float* __restrict__ t,
    const ushort* __restrict__ Wt, ushort* __restrict__ support, int N,
    const int* __restrict__ dst, int* __restrict__ hist,
    int E, int NBUK, int GB)
{
    __shared__ int h[NBUK_MAX];
    const int tid = threadIdx.x;

    if (blockIdx.x >= GB) {
        // ---- histogram branch: chunk = hb, row write contiguous ----
        const int chunk = blockIdx.x - GB;
        for (int i = tid; i < NBUK; i += 256) h[i] = 0;
        __syncthreads();
        const int e0 = chunk * EPB;
        for (int i = tid; i < EPB; i += 256) {
            int e = e0 + i;
            if (e < E) atomicAdd(&h[dst[e] >> 4], 1);
        }
        __syncthreads();
        for (int i = tid; i < NBUK; i += 256)
            hist[(size_t)chunk * NBUK + i] = h[i];
        return;
    }

    // ---- MFMA gemm branch ----
    const int lane = tid & 63;
    const int w    = tid >> 6;
    const int ln   = lane & 15;
    const int q    = lane >> 4;
    const int rowb = blockIdx.x * TILE_ROWS + w * 16;
    const int arow = rowb + ln;

    f32x4 acc[4];
    #pragma unroll
    for (int nt = 0; nt < 4; ++nt)
        #pragma unroll
        for (int r = 0; r < 4; ++r) acc[nt][r] = 0.f;

    const bool aok = (arow < N);
    const float* xrow = &x[(size_t)arow * FIN];

    #pragma unroll
    for (int kc = 0; kc < 4; ++kc) {
        float xs[8];
        #pragma unroll
        for (int j = 0; j < 8; ++j) xs[j] = 0.f;
        if (aok) {
            float4 x0 = *(const float4*)&xrow[kc * 32 + q * 8];
            float4 x1 = *(const float4*)&xrow[kc * 32 + q * 8 + 4];
            xs[0] = x0.x; xs[1] = x0.y; xs[2] = x0.z; xs[3] = x0.w;
            xs[4] = x1.x; xs[5] = x1.y; xs[6] = x1.z; xs[7] = x1.w;
        }
        bf16x8 a;
        #pragma unroll
        for (int j = 0; j < 8; ++j) a[j] = (short)f32_to_bf16_rne(xs[j]);

        #pragma unroll
        for (int nt = 0; nt < 4; ++nt) {
            bf16x8 b = *(const bf16x8*)&Wt[(nt * 16 + ln) * FIN + kc * 32 + q * 8];
            acc[nt] = __builtin_amdgcn_mfma_f32_16x16x32_bf16(a, b, acc[nt], 0, 0, 0);
        }
    }

    #pragma unroll
    for (int reg = 0; reg < 4; ++reg) {
        int r = rowb + q * 4 + reg;
        if (r < N) {
            float tv = t[r];
            #pragma unroll
            for (int nt = 0; nt < 4; ++nt)
                support[(size_t)r * FOUT + nt * 16 + ln] =
                    f32_to_bf16_rne(acc[nt][reg] * tv);
        }
    }
}

// ---------------------------------------------------------------------------
// colscan: per-bucket running sum down the chunk axis, in place.
// hist[c][j] <- sum_{c'<c} cnt[c'][j];  btot[j] <- column total.
// Coalesced row slices; 8-deep row prefetch hides L2/L3 latency.
// ---------------------------------------------------------------------------
__global__ __launch_bounds__(256) void colscan_kernel(
    int* __restrict__ hist, int* __restrict__ btot, int NBUK, int SBP)
{
    const int j = blockIdx.x * 256 + threadIdx.x;
    if (j >= NBUK) return;
    int run = 0;
    for (int c0 = 0; c0 < SBP; c0 += 8) {          // SBP divisible by 8
        int v[8];
        #pragma unroll
        for (int u = 0; u < 8; ++u)
            v[u] = hist[(size_t)(c0 + u) * NBUK + j];
        #pragma unroll
        for (int u = 0; u < 8; ++u) {
            hist[(size_t)(c0 + u) * NBUK + j] = run;
            run += v[u];
        }
    }
    btot[j] = run;
}

// ---------------------------------------------------------------------------
// offscan: single block, exclusive scan of btot -> off[0..NBUK], off[NBUK]=E
// ---------------------------------------------------------------------------
__global__ __launch_bounds__(256) void offscan_kernel(
    const int* __restrict__ btot, int* __restrict__ off, int NBUK, int E)
{
    __shared__ int s[256];
    const int tid = threadIdx.x;
    const int PER = (NBUK + 255) / 256;
    const int lo  = tid * PER;
    const int hi  = min(lo + PER, NBUK);

    int sum = 0;
    for (int j = lo; j < hi; ++j) sum += btot[j];
    s[tid] = sum;
    __syncthreads();
    #pragma unroll
    for (int d = 1; d < 256; d <<= 1) {
        int add = (tid >= d) ? s[tid - d] : 0;
        __syncthreads();
        s[tid] += add;
        __syncthreads();
    }
    int run = (tid == 0) ? 0 : s[tid - 1];
    for (int j = lo; j < hi; ++j) {
        off[j] = run;
        run += btot[j];
    }
    if (tid == 0) off[NBUK] = E;
}

// ---------------------------------------------------------------------------
// coarse scatter: cursors = off[j] + hist[chunk][j] (two contiguous rows).
// LDS int atomics only; chunk XCD-swizzled so adjacent chunks (same XCD)
// write adjacent runs in tmp -> each line dirtied by one XCD.
// rec = {src | (d&15)<<16, ev_bits}
// ---------------------------------------------------------------------------
__global__ __launch_bounds__(256) void coarse_scatter_kernel(
    const int* __restrict__ src, const int* __restrict__ dst,
    const float* __restrict__ ev, const int* __restrict__ hist,
    const int* __restrict__ off, int2* __restrict__ tmp,
    int E, int NBUK, int G)
{
    __shared__ int cur[NBUK_MAX];
    const int tid   = threadIdx.x;
    const int b     = blockIdx.x;
    const int chunk = (b & 7) * G + (b >> 3);
    for (int i = tid; i < NBUK; i += 256)
        cur[i] = off[i] + hist[(size_t)chunk * NBUK + i];
    __syncthreads();

    const int e0 = chunk * EPB;
    for (int i = tid; i < EPB; i += 256) {
        int e = e0 + i;
        if (e < E) {
            int d   = dst[e];
            int pos = atomicAdd(&cur[d >> 4], 1);
            tmp[pos] = make_int2(src[e] | ((d & (NPB - 1)) << 16),
                                 __float_as_int(ev[e]));
        }
    }
}

// ---------------------------------------------------------------------------
// bucket_gather: one block per 16-node bucket (grid 3125 -> 8+ blocks/CU).
// tmp read once into LDS; count -> wave-0 shfl scan -> reorder; then each
// wave walks 4 nodes with BRANCH-FREE per-node loops (flush outside the
// load batch, so the 8-deep loads stay in flight).
// ---------------------------------------------------------------------------
__global__ __launch_bounds__(256) void bucket_gather_kernel(
    const int* __restrict__ off, const int2* __restrict__ tmp,
    const ushort* __restrict__ support, const float* __restrict__ bias,
    float* __restrict__ out, int E, int N, int NBUK)
{
    __shared__ int2 raw[CAP];           // 3.5 KB
    __shared__ int2 sorted[CAP];        // 3.5 KB
    __shared__ int  cnt[NPB];
    __shared__ int  starts[NPB + 1];
    __shared__ int  cur[NPB];

    const int tid   = threadIdx.x;
    const int w     = tid >> 6;
    const int lane  = tid & 63;
    const int B     = blockIdx.x;
    const int node0 = B * NPB;

    const int base   = off[B];
    const int endB   = off[B + 1];
    const int nrec   = endB - base;
    const int placed = (nrec < CAP) ? nrec : CAP;

    if (tid < NPB) cnt[tid] = 0;
    __syncthreads();

    for (int i = tid; i < placed; i += 256) {
        int2 r = tmp[base + i];
        raw[i] = r;
        atomicAdd(&cnt[(r.x >> 16) & (NPB - 1)], 1);
    }
    __syncthreads();

    if (tid < 64) {
        int v   = (tid < NPB) ? cnt[tid] : 0;
        int val = v;
        #pragma unroll
        for (int d = 1; d < NPB; d <<= 1) {
            int n = __shfl_up(val, d);
            if (tid >= d) val += n;
        }
        if (tid < NPB) {
            starts[tid] = val - v;
            cur[tid]    = val - v;
        }
        if (tid == 0) starts[NPB] = placed;
    }
    __syncthreads();

    for (int i = tid; i < placed; i += 256) {
        int2 r  = raw[i];
        int pos = atomicAdd(&cur[(r.x >> 16) & (NPB - 1)], 1);
        sorted[pos] = r;
    }
    __syncthreads();

    const float bv = bias[lane];
    // wave w owns nodes [w*4, (w+1)*4); per-node loop is branch-free
    for (int n = w * 4; n < w * 4 + 4; ++n) {
        const int node = node0 + n;
        int i = starts[n];
        const int e = starts[n + 1];
        float acc = bv;

        while (i + 8 <= e) {
            int2  r[8];
            float v[8];
            #pragma unroll
            for (int u = 0; u < 8; ++u) r[u] = sorted[i + u];
            #pragma unroll
            for (int u = 0; u < 8; ++u)
                v[u] = bf16_to_f32(support[(size_t)(r[u].x & 0xFFFF) * FOUT + lane]);
            #pragma unroll
            for (int u = 0; u < 8; ++u)
                acc += v[u] * __int_as_float(r[u].y);
            i += 8;
        }
        while (i < e) {
            int2 r = sorted[i];
            acc += bf16_to_f32(support[(size_t)(r.x & 0xFFFF) * FOUT + lane])
                   * __int_as_float(r.y);
            ++i;
        }
        if (node < N)
            out[(size_t)node * FOUT + lane] = acc;
    }

    // overflow fallback (never triggers at this size; kept for correctness)
    if (nrec > CAP) {
        __threadfence();
        __syncthreads();
        for (int j = base + CAP + tid; j < endB; j += 256) {
            int2 r = tmp[j];
            int node = node0 + ((r.x >> 16) & (NPB - 1));
            float wgt = __int_as_float(r.y);
            for (int f = 0; f < FOUT; ++f) {
                float v = bf16_to_f32(support[(size_t)(r.x & 0xFFFF) * FOUT + f]);
                atomicAdd(&out[(size_t)node * FOUT + f], v * wgt);
            }
        }
    }
}

extern "C" void kernel_launch(void* const* d_in, const int* in_sizes, int n_in,
                              void* d_out, int out_size, void* d_ws, size_t ws_size,
                              hipStream_t stream) {
    const float* x    = (const float*)d_in[0];
    const float* t    = (const float*)d_in[1];
    const int*   src  = (const int*)d_in[2];
    const int*   dst  = (const int*)d_in[3];
    const float* ev   = (const float*)d_in[4];
    const float* W    = (const float*)d_in[5];
    const float* bias = (const float*)d_in[6];
    float* out = (float*)d_out;

    const int N = in_sizes[1];   // 50000
    const int E = in_sizes[2];   // 800000

    char*   ws      = (char*)d_ws;
    ushort* support = (ushort*)ws;
    ushort* Wt      = (ushort*)(ws + OFF_WT);
    int*    hist    = (int*)(ws + OFF_HIST);
    int*    btot    = (int*)(ws + OFF_BTOT);
    int*    off     = (int*)(ws + OFF_OFF);
    int2*   tmp     = (int2*)(ws + OFF_TMP);

    const int GB   = (N + TILE_ROWS - 1) / TILE_ROWS;   // 782
    const int SBr  = (E + EPB - 1) / EPB;               // 391
    const int SBP  = ((SBr + 7) / 8) * 8;               // 392 (div by 8)
    const int G    = SBP / 8;                           // 49
    const int NBUK = (N + NPB - 1) / NPB;               // 3125
    const int CB   = (NBUK + 255) / 256;                // 13 colscan blocks

    // 0) Wt = bf16(W^T)
    prep_wt_kernel<<<1, 256, 0, stream>>>(W, Wt);

    // 1) fused: MFMA gemm + chunk-major histogram (contiguous row writes)
    gemm_hist_kernel<<<GB + SBP, 256, 0, stream>>>(
        x, t, Wt, support, N, dst, hist, E, NBUK, GB);

    // 2) column running-sum (in place) + per-bucket totals; then off[] scan
    colscan_kernel<<<CB, 256, 0, stream>>>(hist, btot, NBUK, SBP);
    offscan_kernel<<<1, 256, 0, stream>>>(btot, off, NBUK, E);

    // 3) coarse scatter into bucket-ordered tmp (XCD-grouped writes)
    coarse_scatter_kernel<<<SBP, 256, 0, stream>>>(
        src, dst, ev, hist, off, tmp, E, NBUK, G);

    // 4) per-bucket LDS sort + branch-free per-node accumulate -> out (+bias)
    bucket_gather_kernel<<<NBUK, 256, 0, stream>>>(
        off, tmp, support, bias, out, E, N, NBUK);
}

// Round 14
// 157.322 us; speedup vs baseline: 1.0331x; 1.0331x over previous
//
#include <hip/hip_runtime.h>
#include <hip/hip_bf16.h>

#define FIN 128
#define FOUT 64
#define TILE_ROWS 64       // rows per gemm block = 4 waves x 16

#define EPB 2048           // edges per sort chunk
#define NPB 16             // nodes per bucket (d >> 4)
#define NBUK_MAX 3200
#define CAP 448            // records cap per bucket (mean 256, +12 sigma)

// Workspace layout (bytes, 16B-aligned):
//   [0, 6,400,000)             support   : N*64 bf16
//   [6,400,000, +4,900,000)    hist      : NBUK*SBP int, bucket-major [j][c]
//   [11,300,000, +2,400)       blocksums : NBS int (<=300)
//   [11,304,000, +6,400,000)   tmp       : E int2 {src | dloc<<16, ev}
#define OFF_HIST      6400000
#define OFF_BLOCKSUMS 11300000
#define OFF_TMP       11304000

#define SCAN_CHUNK 4096    // elements per scan block (256 thr x 16)

typedef short bf16x8 __attribute__((ext_vector_type(8)));
typedef float f32x4  __attribute__((ext_vector_type(4)));

__device__ inline ushort f32_to_bf16_rne(float f) {
    unsigned u = __float_as_uint(f);
    u += 0x7FFFu + ((u >> 16) & 1u);
    return (ushort)(u >> 16);
}
__device__ inline float bf16_to_f32(ushort h) {
    return __uint_as_float((unsigned)h << 16);
}

// ---------------------------------------------------------------------------
// Fused: blocks [0,GB) MFMA gemm (inline W->bf16, R10-proven); blocks [GB,..)
// coarse dst histogram (bucket-major writes, XCD-swizzled chunks).
// ---------------------------------------------------------------------------
__global__ __launch_bounds__(256) void gemm_hist_kernel(
    const float* __restrict__ x, const float* __restrict__ t,
    const float* __restrict__ W, ushort* __restrict__ support, int N,
    const int* __restrict__ dst, int* __restrict__ hist,
    int E, int SBP, int NBUK, int G, int GB)
{
    __shared__ int h[NBUK_MAX];
    const int tid = threadIdx.x;

    if (blockIdx.x >= GB) {
        // ---- histogram branch ----
        const int hb    = blockIdx.x - GB;
        const int chunk = (hb & 7) * G + (hb >> 3);   // adjacent chunks -> same XCD
        for (int i = tid; i < NBUK; i += 256) h[i] = 0;
        __syncthreads();
        const int e0 = chunk * EPB;
        for (int i = tid; i < EPB; i += 256) {
            int e = e0 + i;
            if (e < E) atomicAdd(&h[dst[e] >> 4], 1);
        }
        __syncthreads();
        for (int i = tid; i < NBUK; i += 256)
            hist[(size_t)i * SBP + chunk] = h[i];
        return;
    }

    // ---- MFMA gemm branch ----
    const int lane = tid & 63;
    const int w    = tid >> 6;
    const int ln   = lane & 15;
    const int q    = lane >> 4;
    const int rowb = blockIdx.x * TILE_ROWS + w * 16;
    const int arow = rowb + ln;

    // B-frags: bfr[kc][nt][j] = bf16(W[kc*32+q*8+j][nt*16+ln])  (L1-hot)
    bf16x8 bfr[4][4];
    #pragma unroll
    for (int kc = 0; kc < 4; ++kc)
        #pragma unroll
        for (int nt = 0; nt < 4; ++nt)
            #pragma unroll
            for (int j = 0; j < 8; ++j)
                bfr[kc][nt][j] = (short)f32_to_bf16_rne(
                    W[(kc * 32 + q * 8 + j) * FOUT + nt * 16 + ln]);

    f32x4 acc[4];
    #pragma unroll
    for (int nt = 0; nt < 4; ++nt)
        #pragma unroll
        for (int r = 0; r < 4; ++r) acc[nt][r] = 0.f;

    const bool aok = (arow < N);
    const float* xrow = &x[(size_t)arow * FIN];

    #pragma unroll
    for (int kc = 0; kc < 4; ++kc) {
        float xs[8];
        #pragma unroll
        for (int j = 0; j < 8; ++j) xs[j] = 0.f;
        if (aok) {
            float4 x0 = *(const float4*)&xrow[kc * 32 + q * 8];
            float4 x1 = *(const float4*)&xrow[kc * 32 + q * 8 + 4];
            xs[0] = x0.x; xs[1] = x0.y; xs[2] = x0.z; xs[3] = x0.w;
            xs[4] = x1.x; xs[5] = x1.y; xs[6] = x1.z; xs[7] = x1.w;
        }
        bf16x8 a;
        #pragma unroll
        for (int j = 0; j < 8; ++j) a[j] = (short)f32_to_bf16_rne(xs[j]);

        #pragma unroll
        for (int nt = 0; nt < 4; ++nt)
            acc[nt] = __builtin_amdgcn_mfma_f32_16x16x32_bf16(a, bfr[kc][nt],
                                                              acc[nt], 0, 0, 0);
    }

    #pragma unroll
    for (int reg = 0; reg < 4; ++reg) {
        int r = rowb + q * 4 + reg;
        if (r < N) {
            float tv = t[r];
            #pragma unroll
            for (int nt = 0; nt < 4; ++nt)
                support[(size_t)r * FOUT + nt * 16 + ln] =
                    f32_to_bf16_rne(acc[nt][reg] * tv);
        }
    }
}

// ---------------------------------------------------------------------------
// scan stage 1: per-block sums of SCAN_CHUNK elements
// ---------------------------------------------------------------------------
__global__ __launch_bounds__(256) void scan_sums_kernel(
    const int* __restrict__ counts, int* __restrict__ blocksums, int M)
{
    __shared__ int red[256];
    const int tid  = threadIdx.x;
    const int base = blockIdx.x * SCAN_CHUNK + tid * 16;

    int s = 0;
    #pragma unroll
    for (int v = 0; v < 4; ++v) {
        int idx = base + v * 4;
        if (idx + 3 < M) {
            int4 c = *(const int4*)&counts[idx];
            s += c.x + c.y + c.z + c.w;
        } else {
            for (int i = 0; i < 4; ++i)
                if (idx + i < M) s += counts[idx + i];
        }
    }
    red[tid] = s;
    __syncthreads();
    #pragma unroll
    for (int d = 128; d > 0; d >>= 1) {
        if (tid < d) red[tid] += red[tid + d];
        __syncthreads();
    }
    if (tid == 0) blocksums[blockIdx.x] = red[0];
}

// ---------------------------------------------------------------------------
// scan stage 2: wave 0 of every block shfl-scans blocksums (64-wide windows)
// for its exclusive offset; then counts[j] <- exclusive prefix in place.
// ---------------------------------------------------------------------------
__global__ __launch_bounds__(256) void scan_apply_kernel(
    int* __restrict__ counts, const int* __restrict__ blocksums, int M, int NB)
{
    __shared__ int s[256];
    __shared__ int bex;
    const int tid  = threadIdx.x;
    const int base = blockIdx.x * SCAN_CHUNK + tid * 16;

    if (tid < 64) {
        int carry = 0;
        for (int w0 = 0; w0 < NB; w0 += 64) {
            int idx = w0 + tid;
            int v   = (idx < NB) ? blocksums[idx] : 0;
            int val = v;
            #pragma unroll
            for (int d = 1; d < 64; d <<= 1) {
                int n = __shfl_up(val, d);
                if (tid >= d) val += n;
            }
            if (idx == (int)blockIdx.x) bex = carry + val - v;
            carry += __shfl(val, 63);
        }
    }

    int c[16];
    int mysum = 0;
    #pragma unroll
    for (int v = 0; v < 4; ++v) {
        int idx = base + v * 4;
        int4 cc = make_int4(0, 0, 0, 0);
        if (idx + 3 < M) {
            cc = *(const int4*)&counts[idx];
        } else {
            if (idx + 0 < M) cc.x = counts[idx + 0];
            if (idx + 1 < M) cc.y = counts[idx + 1];
            if (idx + 2 < M) cc.z = counts[idx + 2];
            if (idx + 3 < M) cc.w = counts[idx + 3];
        }
        c[v * 4 + 0] = cc.x; c[v * 4 + 1] = cc.y;
        c[v * 4 + 2] = cc.z; c[v * 4 + 3] = cc.w;
        mysum += cc.x + cc.y + cc.z + cc.w;
    }
    s[tid] = mysum;
    __syncthreads();
    #pragma unroll
    for (int d = 1; d < 256; d <<= 1) {
        int add = (tid >= d) ? s[tid - d] : 0;
        __syncthreads();
        s[tid] += add;
        __syncthreads();
    }
    int ex = bex + s[tid] - mysum;
    #pragma unroll
    for (int i = 0; i < 16; ++i) {
        if (base + i < M) {
            counts[base + i] = ex;
            ex += c[i];
        }
    }
}

// ---------------------------------------------------------------------------
// coarse scatter: private per-(chunk,bucket) cursors (LDS int atomics only),
// chunk XCD-swizzled. rec = {src | (d&15)<<16, ev_bits}
// ---------------------------------------------------------------------------
__global__ __launch_bounds__(256) void coarse_scatter_kernel(
    const int* __restrict__ src, const int* __restrict__ dst,
    const float* __restrict__ ev, const int* __restrict__ scanned,
    int2* __restrict__ tmp, int E, int SBP, int NBUK, int G)
{
    __shared__ int cur[NBUK_MAX];
    const int tid   = threadIdx.x;
    const int b     = blockIdx.x;
    const int chunk = (b & 7) * G + (b >> 3);
    for (int i = tid; i < NBUK; i += 256)
        cur[i] = scanned[(size_t)i * SBP + chunk];
    __syncthreads();

    const int e0 = chunk * EPB;
    for (int i = tid; i < EPB; i += 256) {
        int e = e0 + i;
        if (e < E) {
            int d   = dst[e];
            int pos = atomicAdd(&cur[d >> 4], 1);
            tmp[pos] = make_int2(src[e] | ((d & (NPB - 1)) << 16),
                                 __float_as_int(ev[e]));
        }
    }
}

// ---------------------------------------------------------------------------
// bucket_gather: one block per 16-node bucket (grid 3125 -> 8 blocks/CU,
// wave-capped). tmp read once into LDS; count -> wave-0 shfl scan ->
// reorder; each wave walks 4 nodes with branch-free per-node loops.
// ---------------------------------------------------------------------------
__global__ __launch_bounds__(256) void bucket_gather_kernel(
    const int* __restrict__ scanned, const int2* __restrict__ tmp,
    const ushort* __restrict__ support, const float* __restrict__ bias,
    float* __restrict__ out, int E, int N, int SBP, int NBUK)
{
    __shared__ int2 raw[CAP];           // 3.5 KB
    __shared__ int2 sorted[CAP];        // 3.5 KB
    __shared__ int  cnt[NPB];
    __shared__ int  starts[NPB + 1];
    __shared__ int  cur[NPB];

    const int tid   = threadIdx.x;
    const int w     = tid >> 6;
    const int lane  = tid & 63;
    const int B     = blockIdx.x;
    const int node0 = B * NPB;

    const int base   = scanned[(size_t)B * SBP];
    const int endB   = (B + 1 < NBUK) ? scanned[(size_t)(B + 1) * SBP] : E;
    const int nrec   = endB - base;
    const int placed = (nrec < CAP) ? nrec : CAP;

    if (tid < NPB) cnt[tid] = 0;
    __syncthreads();

    for (int i = tid; i < placed; i += 256) {
        int2 r = tmp[base + i];
        raw[i] = r;
        atomicAdd(&cnt[(r.x >> 16) & (NPB - 1)], 1);
    }
    __syncthreads();

    if (tid < 64) {
        int v   = (tid < NPB) ? cnt[tid] : 0;
        int val = v;
        #pragma unroll
        for (int d = 1; d < NPB; d <<= 1) {
            int n = __shfl_up(val, d);
            if (tid >= d) val += n;
        }
        if (tid < NPB) {
            starts[tid] = val - v;
            cur[tid]    = val - v;
        }
        if (tid == 0) starts[NPB] = placed;
    }
    __syncthreads();

    for (int i = tid; i < placed; i += 256) {
        int2 r  = raw[i];
        int pos = atomicAdd(&cur[(r.x >> 16) & (NPB - 1)], 1);
        sorted[pos] = r;
    }
    __syncthreads();

    const float bv = bias[lane];
    // wave w owns nodes [w*4, (w+1)*4); per-node loop is branch-free
    for (int n = w * 4; n < w * 4 + 4; ++n) {
        const int node = node0 + n;
        int i = starts[n];
        const int e = starts[n + 1];
        float acc = bv;

        while (i + 8 <= e) {
            int2  r[8];
            float v[8];
            #pragma unroll
            for (int u = 0; u < 8; ++u) r[u] = sorted[i + u];
            #pragma unroll
            for (int u = 0; u < 8; ++u)
                v[u] = bf16_to_f32(support[(size_t)(r[u].x & 0xFFFF) * FOUT + lane]);
            #pragma unroll
            for (int u = 0; u < 8; ++u)
                acc += v[u] * __int_as_float(r[u].y);
            i += 8;
        }
        while (i < e) {
            int2 r = sorted[i];
            acc += bf16_to_f32(support[(size_t)(r.x & 0xFFFF) * FOUT + lane])
                   * __int_as_float(r.y);
            ++i;
        }
        if (node < N)
            out[(size_t)node * FOUT + lane] = acc;
    }

    // overflow fallback (never triggers at this size; kept for correctness)
    if (nrec > CAP) {
        __threadfence();
        __syncthreads();
        for (int j = base + CAP + tid; j < endB; j += 256) {
            int2 r = tmp[j];
            int node = node0 + ((r.x >> 16) & (NPB - 1));
            float wgt = __int_as_float(r.y);
            for (int f = 0; f < FOUT; ++f) {
                float v = bf16_to_f32(support[(size_t)(r.x & 0xFFFF) * FOUT + f]);
                atomicAdd(&out[(size_t)node * FOUT + f], v * wgt);
            }
        }
    }
}

extern "C" void kernel_launch(void* const* d_in, const int* in_sizes, int n_in,
                              void* d_out, int out_size, void* d_ws, size_t ws_size,
                              hipStream_t stream) {
    const float* x    = (const float*)d_in[0];
    const float* t    = (const float*)d_in[1];
    const int*   src  = (const int*)d_in[2];
    const int*   dst  = (const int*)d_in[3];
    const float* ev   = (const float*)d_in[4];
    const float* W    = (const float*)d_in[5];
    const float* bias = (const float*)d_in[6];
    float* out = (float*)d_out;

    const int N = in_sizes[1];   // 50000
    const int E = in_sizes[2];   // 800000

    char*   ws        = (char*)d_ws;
    ushort* support   = (ushort*)ws;
    int*    hist      = (int*)(ws + OFF_HIST);
    int*    blocksums = (int*)(ws + OFF_BLOCKSUMS);
    int2*   tmp       = (int2*)(ws + OFF_TMP);

    const int GB   = (N + TILE_ROWS - 1) / TILE_ROWS;       // 782
    const int SBr  = (E + EPB - 1) / EPB;                   // 391
    const int SBP  = ((SBr + 7) / 8) * 8;                   // 392
    const int G    = SBP / 8;                               // 49
    const int NBUK = (N + NPB - 1) / NPB;                   // 3125
    const int M    = NBUK * SBP;                            // 1,225,000
    const int NBS  = (M + SCAN_CHUNK - 1) / SCAN_CHUNK;     // 300

    // 1) fused: MFMA gemm (inline W->bf16) + coarse histogram
    gemm_hist_kernel<<<GB + SBP, 256, 0, stream>>>(
        x, t, W, support, N, dst, hist, E, SBP, NBUK, G, GB);

    // 2) scan: per-block sums, then apply (top-level scan inlined)
    scan_sums_kernel<<<NBS, 256, 0, stream>>>(hist, blocksums, M);
    scan_apply_kernel<<<NBS, 256, 0, stream>>>(hist, blocksums, M, NBS);

    // 3) coarse scatter into bucket-ordered tmp (XCD-grouped writes)
    coarse_scatter_kernel<<<SBP, 256, 0, stream>>>(
        src, dst, ev, hist, tmp, E, SBP, NBUK, G);

    // 4) per-bucket LDS sort + branch-free per-node accumulate -> out (+bias)
    bucket_gather_kernel<<<NBUK, 256, 0, stream>>>(
        hist, tmp, support, bias, out, E, N, SBP, NBUK);
}

// Round 15
// 142.704 us; speedup vs baseline: 1.1389x; 1.1024x over previous
//
#include <hip/hip_runtime.h>
#include <hip/hip_bf16.h>

#define FIN 128
#define FOUT 64
#define TILE_ROWS 64       // rows per gemm block = 4 waves x 16

#define EPB 2048           // edges per sort chunk
#define NPB 32             // nodes per bucket (d >> 5)
#define NBUK_MAX 1600
#define CAP 768            // records cap per bucket (mean 512, +11 sigma)

// Workspace layout (bytes, 16B-aligned):
//   [0, 6,400,000)            support   : N*64 bf16
//   [6,400,000, +2,450,784)   hist      : NBUK*SBP int, bucket-major [j][c]
//   [8,860,000, +2,400)       blocksums : NBS int
//   [8,861,024, +6,400,000)   tmp       : E int2 {src | dloc<<16, ev}
#define OFF_HIST      6400000
#define OFF_BLOCKSUMS 8860000
#define OFF_TMP       8861024

#define SCAN_CHUNK 4096    // elements per scan block (256 thr x 16)

typedef short bf16x8 __attribute__((ext_vector_type(8)));
typedef float f32x4  __attribute__((ext_vector_type(4)));

__device__ inline ushort f32_to_bf16_rne(float f) {
    unsigned u = __float_as_uint(f);
    u += 0x7FFFu + ((u >> 16) & 1u);
    return (ushort)(u >> 16);
}
__device__ inline float bf16_to_f32(ushort h) {
    return __uint_as_float((unsigned)h << 16);
}

// ---------------------------------------------------------------------------
// Fused: blocks [0,GB) MFMA gemm (inline W->bf16); blocks [GB,..) coarse
// dst histogram (bucket-major writes, XCD-swizzled chunks).
// ---------------------------------------------------------------------------
__global__ __launch_bounds__(256) void gemm_hist_kernel(
    const float* __restrict__ x, const float* __restrict__ t,
    const float* __restrict__ W, ushort* __restrict__ support, int N,
    const int* __restrict__ dst, int* __restrict__ hist,
    int E, int SBP, int NBUK, int G, int GB)
{
    __shared__ int h[NBUK_MAX];
    const int tid = threadIdx.x;

    if (blockIdx.x >= GB) {
        // ---- histogram branch ----
        const int hb    = blockIdx.x - GB;
        const int chunk = (hb & 7) * G + (hb >> 3);   // adjacent chunks -> same XCD
        for (int i = tid; i < NBUK; i += 256) h[i] = 0;
        __syncthreads();
        const int e0 = chunk * EPB;
        for (int i = tid; i < EPB; i += 256) {
            int e = e0 + i;
            if (e < E) atomicAdd(&h[dst[e] >> 5], 1);
        }
        __syncthreads();
        for (int i = tid; i < NBUK; i += 256)
            hist[i * SBP + chunk] = h[i];
        return;
    }

    // ---- MFMA gemm branch ----
    const int lane = tid & 63;
    const int w    = tid >> 6;          // wave 0..3
    const int ln   = lane & 15;
    const int q    = lane >> 4;         // quad 0..3
    const int rowb = blockIdx.x * TILE_ROWS + w * 16;
    const int arow = rowb + ln;

    f32x4 acc[4];
    #pragma unroll
    for (int nt = 0; nt < 4; ++nt)
        #pragma unroll
        for (int r = 0; r < 4; ++r) acc[nt][r] = 0.f;

    const bool aok = (arow < N);
    const float* xrow = &x[(size_t)arow * FIN];

    #pragma unroll
    for (int kc = 0; kc < 4; ++kc) {
        float xs[8];
        #pragma unroll
        for (int j = 0; j < 8; ++j) xs[j] = 0.f;
        if (aok) {
            float4 x0 = *(const float4*)&xrow[kc * 32 + q * 8];
            float4 x1 = *(const float4*)&xrow[kc * 32 + q * 8 + 4];
            xs[0] = x0.x; xs[1] = x0.y; xs[2] = x0.z; xs[3] = x0.w;
            xs[4] = x1.x; xs[5] = x1.y; xs[6] = x1.z; xs[7] = x1.w;
        }
        bf16x8 a;
        #pragma unroll
        for (int j = 0; j < 8; ++j) a[j] = (short)f32_to_bf16_rne(xs[j]);

        #pragma unroll
        for (int nt = 0; nt < 4; ++nt) {
            bf16x8 b;
            #pragma unroll
            for (int j = 0; j < 8; ++j)
                b[j] = (short)f32_to_bf16_rne(
                    W[(kc * 32 + q * 8 + j) * FOUT + nt * 16 + ln]);
            acc[nt] = __builtin_amdgcn_mfma_f32_16x16x32_bf16(a, b, acc[nt], 0, 0, 0);
        }
    }

    // epilogue: D[m=q*4+reg][n=ln]; scale by t[row]; store bf16
    #pragma unroll
    for (int reg = 0; reg < 4; ++reg) {
        int r = rowb + q * 4 + reg;
        if (r < N) {
            float tv = t[r];
            #pragma unroll
            for (int nt = 0; nt < 4; ++nt)
                support[(size_t)r * FOUT + nt * 16 + ln] =
                    f32_to_bf16_rne(acc[nt][reg] * tv);
        }
    }
}

// ---------------------------------------------------------------------------
// scan stage 1: per-block sums of SCAN_CHUNK elements
// ---------------------------------------------------------------------------
__global__ __launch_bounds__(256) void scan_sums_kernel(
    const int* __restrict__ counts, int* __restrict__ blocksums, int M)
{
    __shared__ int red[256];
    const int tid  = threadIdx.x;
    const int base = blockIdx.x * SCAN_CHUNK + tid * 16;

    int s = 0;
    #pragma unroll
    for (int v = 0; v < 4; ++v) {
        int idx = base + v * 4;
        if (idx + 3 < M) {
            int4 c = *(const int4*)&counts[idx];
            s += c.x + c.y + c.z + c.w;
        } else {
            for (int i = 0; i < 4; ++i)
                if (idx + i < M) s += counts[idx + i];
        }
    }
    red[tid] = s;
    __syncthreads();
    #pragma unroll
    for (int d = 128; d > 0; d >>= 1) {
        if (tid < d) red[tid] += red[tid + d];
        __syncthreads();
    }
    if (tid == 0) blocksums[blockIdx.x] = red[0];
}

// ---------------------------------------------------------------------------
// scan stage 2: wave 0 of every block shfl-scans blocksums (64-wide windows)
// for its exclusive offset; then counts[j] <- exclusive prefix in place.
// ---------------------------------------------------------------------------
__global__ __launch_bounds__(256) void scan_apply_kernel(
    int* __restrict__ counts, const int* __restrict__ blocksums, int M, int NB)
{
    __shared__ int s[256];
    __shared__ int bex;
    const int tid  = threadIdx.x;
    const int base = blockIdx.x * SCAN_CHUNK + tid * 16;

    if (tid < 64) {
        int carry = 0;
        for (int w0 = 0; w0 < NB; w0 += 64) {
            int idx = w0 + tid;
            int v   = (idx < NB) ? blocksums[idx] : 0;
            int val = v;
            #pragma unroll
            for (int d = 1; d < 64; d <<= 1) {
                int n = __shfl_up(val, d);
                if (tid >= d) val += n;
            }
            if (idx == (int)blockIdx.x) bex = carry + val - v;
            carry += __shfl(val, 63);
        }
    }

    int c[16];
    int mysum = 0;
    #pragma unroll
    for (int v = 0; v < 4; ++v) {
        int idx = base + v * 4;
        int4 cc = make_int4(0, 0, 0, 0);
        if (idx + 3 < M) {
            cc = *(const int4*)&counts[idx];
        } else {
            if (idx + 0 < M) cc.x = counts[idx + 0];
            if (idx + 1 < M) cc.y = counts[idx + 1];
            if (idx + 2 < M) cc.z = counts[idx + 2];
            if (idx + 3 < M) cc.w = counts[idx + 3];
        }
        c[v * 4 + 0] = cc.x; c[v * 4 + 1] = cc.y;
        c[v * 4 + 2] = cc.z; c[v * 4 + 3] = cc.w;
        mysum += cc.x + cc.y + cc.z + cc.w;
    }
    s[tid] = mysum;
    __syncthreads();
    #pragma unroll
    for (int d = 1; d < 256; d <<= 1) {
        int add = (tid >= d) ? s[tid - d] : 0;
        __syncthreads();
        s[tid] += add;
        __syncthreads();
    }
    int ex = bex + s[tid] - mysum;
    #pragma unroll
    for (int i = 0; i < 16; ++i) {
        if (base + i < M) {
            counts[base + i] = ex;
            ex += c[i];
        }
    }
}

// ---------------------------------------------------------------------------
// coarse scatter: private per-(chunk,bucket) cursors (LDS int atomics only),
// chunk XCD-swizzled so adjacent chunks' runs dirty lines in ONE L2.
// rec = {src | (d&31)<<16, ev_bits}   (src < 65536: N = 50000 ok)
// ---------------------------------------------------------------------------
__global__ __launch_bounds__(256) void coarse_scatter_kernel(
    const int* __restrict__ src, const int* __restrict__ dst,
    const float* __restrict__ ev, const int* __restrict__ scanned,
    int2* __restrict__ tmp, int E, int SBP, int NBUK, int G)
{
    __shared__ int cur[NBUK_MAX];
    const int tid   = threadIdx.x;
    const int b     = blockIdx.x;
    const int chunk = (b & 7) * G + (b >> 3);
    for (int i = tid; i < NBUK; i += 256)
        cur[i] = scanned[i * SBP + chunk];
    __syncthreads();

    const int e0 = chunk * EPB;
    for (int i = tid; i < EPB; i += 256) {
        int e = e0 + i;
        if (e < E) {
            int d   = dst[e];
            int pos = atomicAdd(&cur[d >> 5], 1);
            tmp[pos] = make_int2(src[e] | ((d & (NPB - 1)) << 16),
                                 __float_as_int(ev[e]));
        }
    }
}

// ---------------------------------------------------------------------------
// bucket_gather: one block per 32-node bucket. tmp read once into LDS;
// count (int atomics) -> wave-0 shfl scan -> reorder -> register-walk with
// 4-deep MLP and wave-uniform node-boundary flush. No float atomics.
// ---------------------------------------------------------------------------
__global__ __launch_bounds__(256) void bucket_gather_kernel(
    const int* __restrict__ scanned, const int2* __restrict__ tmp,
    const ushort* __restrict__ support, const float* __restrict__ bias,
    float* __restrict__ out, int E, int N, int SBP, int NBUK)
{
    __shared__ int2 raw[CAP];           // 6 KB
    __shared__ int2 sorted[CAP];        // 6 KB
    __shared__ int  cnt[NPB];
    __shared__ int  starts[NPB + 1];
    __shared__ int  cur[NPB];

    const int tid   = threadIdx.x;
    const int w     = tid >> 6;
    const int lane  = tid & 63;
    const int B     = blockIdx.x;
    const int node0 = B * NPB;

    const int base   = scanned[B * SBP];
    const int endB   = (B + 1 < NBUK) ? scanned[(B + 1) * SBP] : E;
    const int nrec   = endB - base;
    const int placed = (nrec < CAP) ? nrec : CAP;

    if (tid < NPB) cnt[tid] = 0;
    __syncthreads();

    // single global read of tmp: stage + count
    for (int i = tid; i < placed; i += 256) {
        int2 r = tmp[base + i];
        raw[i] = r;
        atomicAdd(&cnt[(r.x >> 16) & (NPB - 1)], 1);
    }
    __syncthreads();

    // wave-0 shfl scan over 32 counters
    if (tid < 64) {
        int v   = (tid < NPB) ? cnt[tid] : 0;
        int val = v;
        #pragma unroll
        for (int d = 1; d < NPB; d <<= 1) {
            int n = __shfl_up(val, d);
            if (tid >= d) val += n;
        }
        if (tid < NPB) {
            starts[tid] = val - v;
            cur[tid]    = val - v;
        }
        if (tid == 0) starts[NPB] = placed;
    }
    __syncthreads();

    // reorder LDS -> LDS
    for (int i = tid; i < placed; i += 256) {
        int2 r  = raw[i];
        int pos = atomicAdd(&cur[(r.x >> 16) & (NPB - 1)], 1);
        sorted[pos] = r;
    }
    __syncthreads();

    // walk: wave w owns nodes [w*8, (w+1)*8) == records [rbeg, rend)
    const float bv = bias[lane];
    const int rbeg = starts[w * 8];
    const int rend = starts[w * 8 + 8];

    float accv = 0.f;
    int   curn = -1;

    int i = rbeg;
    while (i < rend) {
        if (i + 4 <= rend) {
            int2 a = sorted[i], b = sorted[i + 1], c = sorted[i + 2], d = sorted[i + 3];
            float va = bf16_to_f32(support[(size_t)(a.x & 0xFFFF) * FOUT + lane]);
            float vb = bf16_to_f32(support[(size_t)(b.x & 0xFFFF) * FOUT + lane]);
            float vc = bf16_to_f32(support[(size_t)(c.x & 0xFFFF) * FOUT + lane]);
            float vd = bf16_to_f32(support[(size_t)(d.x & 0xFFFF) * FOUT + lane]);
            int2  rs[4] = {a, b, c, d};
            float vs[4] = {va, vb, vc, vd};
            #pragma unroll
            for (int qq = 0; qq < 4; ++qq) {
                int n = (rs[qq].x >> 16) & (NPB - 1);   // wave-uniform
                if (n != curn) {
                    if (curn >= 0 && node0 + curn < N)
                        out[(size_t)(node0 + curn) * FOUT + lane] = accv + bv;
                    curn = n;
                    accv = 0.f;
                }
                accv += vs[qq] * __int_as_float(rs[qq].y);
            }
            i += 4;
        } else {
            int2 a = sorted[i];
            float va = bf16_to_f32(support[(size_t)(a.x & 0xFFFF) * FOUT + lane]);
            int n = (a.x >> 16) & (NPB - 1);
            if (n != curn) {
                if (curn >= 0 && node0 + curn < N)
                    out[(size_t)(node0 + curn) * FOUT + lane] = accv + bv;
                curn = n;
                accv = 0.f;
            }
            accv += va * __int_as_float(a.y);
            i += 1;
        }
    }
    if (curn >= 0 && node0 + curn < N)
        out[(size_t)(node0 + curn) * FOUT + lane] = accv + bv;

    // zero-count nodes get bias rows
    for (int n = w; n < NPB; n += 4) {
        int node = node0 + n;
        if (node < N && cnt[n] == 0)
            out[(size_t)node * FOUT + lane] = bv;
    }

    // overflow fallback (never triggers at this size; kept for correctness)
    if (nrec > CAP) {
        __threadfence();
        __syncthreads();
        for (int j = base + CAP + tid; j < endB; j += 256) {
            int2 r = tmp[j];
            int node = node0 + ((r.x >> 16) & (NPB - 1));
            float wgt = __int_as_float(r.y);
            for (int f = 0; f < FOUT; ++f) {
                float v = bf16_to_f32(support[(size_t)(r.x & 0xFFFF) * FOUT + f]);
                atomicAdd(&out[(size_t)node * FOUT + f], v * wgt);
            }
        }
    }
}

extern "C" void kernel_launch(void* const* d_in, const int* in_sizes, int n_in,
                              void* d_out, int out_size, void* d_ws, size_t ws_size,
                              hipStream_t stream) {
    const float* x    = (const float*)d_in[0];
    const float* t    = (const float*)d_in[1];
    const int*   src  = (const int*)d_in[2];
    const int*   dst  = (const int*)d_in[3];
    const float* ev   = (const float*)d_in[4];
    const float* W    = (const float*)d_in[5];
    const float* bias = (const float*)d_in[6];
    float* out = (float*)d_out;

    const int N = in_sizes[1];   // 50000
    const int E = in_sizes[2];   // 800000

    char*   ws        = (char*)d_ws;
    ushort* support   = (ushort*)ws;
    int*    hist      = (int*)(ws + OFF_HIST);
    int*    blocksums = (int*)(ws + OFF_BLOCKSUMS);
    int2*   tmp       = (int2*)(ws + OFF_TMP);

    const int GB   = (N + TILE_ROWS - 1) / TILE_ROWS;       // 782
    const int SBr  = (E + EPB - 1) / EPB;                   // 391
    const int SBP  = ((SBr + 7) / 8) * 8;                   // 392
    const int G    = SBP / 8;                               // 49
    const int NBUK = (N + NPB - 1) / NPB;                   // 1563
    const int M    = NBUK * SBP;                            // 612,696
    const int NBS  = (M + SCAN_CHUNK - 1) / SCAN_CHUNK;     // 150 (<=256)

    // 1) fused: MFMA gemm (inline W->bf16) + coarse histogram
    gemm_hist_kernel<<<GB + SBP, 256, 0, stream>>>(
        x, t, W, support, N, dst, hist, E, SBP, NBUK, G, GB);

    // 2) scan: per-block sums, then apply (top-level scan inlined)
    scan_sums_kernel<<<NBS, 256, 0, stream>>>(hist, blocksums, M);
    scan_apply_kernel<<<NBS, 256, 0, stream>>>(hist, blocksums, M, NBS);

    // 3) coarse scatter into bucket-ordered tmp (XCD-grouped writes)
    coarse_scatter_kernel<<<SBP, 256, 0, stream>>>(
        src, dst, ev, hist, tmp, E, SBP, NBUK, G);

    // 4) per-bucket LDS sort + register-walk accumulate -> out (+bias)
    bucket_gather_kernel<<<NBUK, 256, 0, stream>>>(
        hist, tmp, support, bias, out, E, N, SBP, NBUK);
}